// Round 8
// baseline (12900.914 us; speedup 1.0000x reference)
//
#include <hip/hip_runtime.h>
#include <hip/hip_bf16.h>
#include <stdint.h>

#define DEV __device__ __forceinline__
typedef unsigned short u16;
typedef unsigned int   u32;

static constexpr int SS = 256;   // src len
static constexpr int TT = 64;    // tgt len
static constexpr int EE = 256;   // embed dim
static constexpr int HH = 512;   // hidden
static constexpr int G3 = 1536;  // 3*H
static constexpr int VV = 32000; // vocab

using frag   = __attribute__((ext_vector_type(8))) short;  // 8 bf16 (4 VGPR)
using f32x4v = __attribute__((ext_vector_type(4))) float;  // MFMA acc

// ---------- helpers ----------
DEV float blo(u32 u){ union{u32 i; float f;} x; x.i = u << 16;         return x.f; }
DEV float bhi(u32 u){ union{u32 i; float f;} x; x.i = u & 0xffff0000u; return x.f; }
DEV float bf2f(u16 u){ union{u32 i; float f;} x; x.i = ((u32)u) << 16; return x.f; }
DEV u16 f2bf(float f){ union{float f; u32 u;} v; v.f = f;
  u32 r = v.u + 0x7fffu + ((v.u >> 16) & 1u); return (u16)(r >> 16); }
DEV float sigf (float x){ return 1.0f / (1.0f + __expf(-x)); }
DEV float tanh_(float x){ return 1.0f - 2.0f / (1.0f + __expf(2.0f * x)); }
DEV void unp8(float* d, uint4 u){
  d[0]=blo(u.x); d[1]=bhi(u.x); d[2]=blo(u.y); d[3]=bhi(u.y);
  d[4]=blo(u.z); d[5]=bhi(u.z); d[6]=blo(u.w); d[7]=bhi(u.w);
}
DEV float dot4(float acc, float4 w, float4 x){
  acc = fmaf(w.x,x.x,acc); acc = fmaf(w.y,x.y,acc);
  acc = fmaf(w.z,x.z,acc); acc = fmaf(w.w,x.w,acc);
  return acc;
}
DEV float fma8(float acc, const float* w, float4 a, float4 b){
  acc = fmaf(w[0],a.x,acc); acc = fmaf(w[1],a.y,acc);
  acc = fmaf(w[2],a.z,acc); acc = fmaf(w[3],a.w,acc);
  acc = fmaf(w[4],b.x,acc); acc = fmaf(w[5],b.y,acc);
  acc = fmaf(w[6],b.z,acc); acc = fmaf(w[7],b.w,acc);
  return acc;
}

// ---------- K0: weight transpose  Wt[(k4*NR + r)*4+e] = W[r*stride + c0 + k4*4+e]
__global__ __launch_bounds__(256)
void k_wt(const float* __restrict__ W, float* __restrict__ Wt,
          int NR, int stride, int c0)
{
  int idx = blockIdx.x * 256 + threadIdx.x;
  if (idx >= NR * 128) return;
  int r = idx >> 7, k4 = idx & 127;
  float4 v = *(const float4*)(W + (size_t)r * stride + c0 + k4 * 4);
  *(float4*)(Wt + ((size_t)k4 * NR + r) * 4) = v;
}

// ---------- K1: gi = gather(emb, tok) @ W[:, :256]^T + bih  (bf16 out) ----
__global__ __launch_bounds__(256)
void k_embed_gemm(const int* __restrict__ tok, int Tlen,
                  const float* __restrict__ emb,
                  const float* __restrict__ W, int wstride,
                  const float* __restrict__ bias,
                  u16* __restrict__ gi)
{
  __shared__ float es[16][EE];
  const int tid = threadIdx.x;
  const int r0 = blockIdx.y * 16;
  #pragma unroll
  for (int rr = 0; rr < 16; ++rr) {
    int r = r0 + rr;
    int token = tok[(r & 31) * Tlen + (r >> 5)];
    es[rr][tid] = emb[(size_t)token * EE + tid];
  }
  __syncthreads();
  const int jl = tid & 63;
  const int rg = (tid >> 6) << 2;
  const int jbase = blockIdx.x * 256 + jl;
  float acc[4][4];
  #pragma unroll
  for (int jj = 0; jj < 4; ++jj) {
    float bv = bias[jbase + jj * 64];
    #pragma unroll
    for (int rr = 0; rr < 4; ++rr) acc[jj][rr] = bv;
  }
  const float4* w0 = (const float4*)(W + (size_t)(jbase      ) * wstride);
  const float4* w1 = (const float4*)(W + (size_t)(jbase +  64) * wstride);
  const float4* w2 = (const float4*)(W + (size_t)(jbase + 128) * wstride);
  const float4* w3 = (const float4*)(W + (size_t)(jbase + 192) * wstride);
  for (int k4 = 0; k4 < EE / 4; ++k4) {
    float4 wv0 = w0[k4], wv1 = w1[k4], wv2 = w2[k4], wv3 = w3[k4];
    #pragma unroll
    for (int rr = 0; rr < 4; ++rr) {
      float4 e = *(const float4*)&es[rg + rr][k4 * 4];
      acc[0][rr] = dot4(acc[0][rr], wv0, e);
      acc[1][rr] = dot4(acc[1][rr], wv1, e);
      acc[2][rr] = dot4(acc[2][rr], wv2, e);
      acc[3][rr] = dot4(acc[3][rr], wv3, e);
    }
  }
  #pragma unroll
  for (int rr = 0; rr < 4; ++rr)
    #pragma unroll
    for (int jj = 0; jj < 4; ++jj)
      gi[(size_t)(r0 + rg + rr) * G3 + jbase + jj * 64] = f2bf(acc[jj][rr]);
}

// ---------- K2: encoder scan — ONE BLOCK PER BATCH ELEMENT (32 blocks) ----
// No grid sync: recurrence independent across b. h f32 in LDS all 256 steps.
// eWt: transposed Whh [k4][1536][4] -> lane-coalesced float4 reads.
__global__ __launch_bounds__(512)
void k_enc_scan_pb(const u16* __restrict__ gi, const float* __restrict__ eWt,
                   const float* __restrict__ bhh, u16* __restrict__ enc_outs,
                   float* __restrict__ hT)
{
  __shared__ float h[2][HH];
  const int b = blockIdx.x;
  const int i = threadIdx.x;
  const float bR = bhh[i], bZ = bhh[i + 512], bN = bhh[i + 1024];
  h[0][i] = 0.f;
  __syncthreads();
  const float4* wt = (const float4*)eWt;
  for (int t = 0; t < SS; ++t) {
    const float* hc = h[t & 1];
    float aR0=0.f, aR1=0.f, aZ0=0.f, aZ1=0.f, aN0=0.f, aN1=0.f;
    for (int k4 = 0; k4 < 128; k4 += 2) {
      float4 h0 = *(const float4*)&hc[k4 * 4];
      float4 h1 = *(const float4*)&hc[k4 * 4 + 4];
      aR0 = dot4(aR0, wt[(size_t)k4 * G3 + i],              h0);
      aZ0 = dot4(aZ0, wt[(size_t)k4 * G3 + 512 + i],        h0);
      aN0 = dot4(aN0, wt[(size_t)k4 * G3 + 1024 + i],       h0);
      aR1 = dot4(aR1, wt[(size_t)(k4+1) * G3 + i],          h1);
      aZ1 = dot4(aZ1, wt[(size_t)(k4+1) * G3 + 512 + i],    h1);
      aN1 = dot4(aN1, wt[(size_t)(k4+1) * G3 + 1024 + i],   h1);
    }
    const float aR = aR0 + aR1, aZ = aZ0 + aZ1, aN = aN0 + aN1;
    const size_t g = ((size_t)t * 32 + b) * G3;
    float r = sigf (bf2f(gi[g +        i]) + aR + bR);
    float z = sigf (bf2f(gi[g +  512 + i]) + aZ + bZ);
    float n = tanh_(bf2f(gi[g + 1024 + i]) + r * (aN + bN));
    float h2 = z * hc[i] + (1.f - z) * n;
    h[(t + 1) & 1][i] = h2;
    enc_outs[((size_t)b * 256 + t) * 512 + i] = f2bf(h2);
    __syncthreads();
  }
  hT[b * 512 + i] = h[0][i];   // SS even -> final state in h[0]
}

// ---------- K3: enc_proj = enc_outs @ attn_W2^T + b2 ----------
__global__ __launch_bounds__(256)
void k_proj(const u16* __restrict__ A, const float* __restrict__ W,
            const float* __restrict__ bias, u16* __restrict__ Out)
{
  __shared__ float es[16][HH];
  const int tid = threadIdx.x;
  const int r0 = blockIdx.y * 16;
  #pragma unroll
  for (int j = 0; j < 4; ++j) {
    int u = j * 256 + tid;
    int row = u >> 6, k = (u & 63) * 8;
    float d[8]; unp8(d, *(const uint4*)(A + (size_t)(r0 + row) * HH + k));
    *(float4*)&es[row][k]     = make_float4(d[0],d[1],d[2],d[3]);
    *(float4*)&es[row][k + 4] = make_float4(d[4],d[5],d[6],d[7]);
  }
  __syncthreads();
  const int jl = tid & 63;
  const int rg = (tid >> 6) << 2;
  const int jbase = blockIdx.x * 256 + jl;
  float acc[4][4];
  #pragma unroll
  for (int jj = 0; jj < 4; ++jj) {
    float bv = bias[jbase + jj * 64];
    #pragma unroll
    for (int rr = 0; rr < 4; ++rr) acc[jj][rr] = bv;
  }
  const float4* w0 = (const float4*)(W + (size_t)(jbase      ) * HH);
  const float4* w1 = (const float4*)(W + (size_t)(jbase +  64) * HH);
  const float4* w2 = (const float4*)(W + (size_t)(jbase + 128) * HH);
  const float4* w3 = (const float4*)(W + (size_t)(jbase + 192) * HH);
  for (int k4 = 0; k4 < HH / 4; ++k4) {
    float4 wv0 = w0[k4], wv1 = w1[k4], wv2 = w2[k4], wv3 = w3[k4];
    #pragma unroll
    for (int rr = 0; rr < 4; ++rr) {
      float4 e = *(const float4*)&es[rg + rr][k4 * 4];
      acc[0][rr] = dot4(acc[0][rr], wv0, e);
      acc[1][rr] = dot4(acc[1][rr], wv1, e);
      acc[2][rr] = dot4(acc[2][rr], wv2, e);
      acc[3][rr] = dot4(acc[3][rr], wv3, e);
    }
  }
  #pragma unroll
  for (int rr = 0; rr < 4; ++rr)
    #pragma unroll
    for (int jj = 0; jj < 4; ++jj)
      Out[(size_t)(r0 + rg + rr) * HH + jbase + jj * 64] = f2bf(acc[jj][rr]);
}

// ---------- K4: decoder scan — ONE BLOCK PER BATCH ELEMENT (32 blocks) ----
// All phases in-block; only __syncthreads. Softmax without max-shift
// (validated round 7: |scores| < ~5). Transposed weights, h f32 in LDS.
__global__ __launch_bounds__(512)
void k_dec_scan_pb(const u16* __restrict__ gi, const float* __restrict__ hT,
                   const float* __restrict__ dW1t, const float* __restrict__ b1,
                   const float* __restrict__ av,
                   const u16* __restrict__ enc_proj, const u16* __restrict__ enc_outs,
                   const float* __restrict__ dWht, const float* __restrict__ dWit,
                   const float* __restrict__ bhh, u16* __restrict__ h2bf)
{
  __shared__ float h[2][HH], a_[HH], vs_[HH], ctx[HH];
  __shared__ float scL[256], wts[256], part[8];
  const int b = blockIdx.x;
  const int i = threadIdx.x;
  const float bR = bhh[i], bZ = bhh[i + 512], bN = bhh[i + 1024];
  const float b1i = b1[i];
  h[0][i] = hT[b * 512 + i];
  vs_[i] = av[i];
  __syncthreads();
  const float4* w1t = (const float4*)dW1t;
  const float4* wht = (const float4*)dWht;
  const float4* wit = (const float4*)dWit;
  for (int t = 0; t < TT; ++t) {
    const float* hc = h[t & 1];
    // ---- P1: a_[i] = b1[i] + h . W1[i,:] ----
    {
      float a0 = 0.f, a1 = 0.f;
      for (int k4 = 0; k4 < 128; k4 += 2) {
        a0 = dot4(a0, w1t[(size_t)k4 * HH + i],       *(const float4*)&hc[k4 * 4]);
        a1 = dot4(a1, w1t[(size_t)(k4+1) * HH + i],   *(const float4*)&hc[k4 * 4 + 4]);
      }
      a_[i] = a0 + a1 + b1i;
    }
    __syncthreads();
    // ---- P2: scores (2 threads per s) ----
    {
      const int s = i >> 1, kh = i & 1;
      const uint4* pr = (const uint4*)(enc_proj + ((size_t)b * 256 + s) * 512 + kh * 256);
      const float* ak = a_ + kh * 256;
      const float* vk = vs_ + kh * 256;
      float sc = 0.f;
      for (int k8 = 0; k8 < 32; ++k8) {
        float d[8]; unp8(d, pr[k8]);
        #pragma unroll
        for (int e = 0; e < 8; ++e)
          sc += vk[k8 * 8 + e] * tanh_(d[e] + ak[k8 * 8 + e]);
      }
      sc += __shfl_xor(sc, 1);
      if (kh == 0) scL[s] = sc;
    }
    __syncthreads();
    // softmax over 256 scores (no max-shift; bounded scores)
    {
      float e = (i < 256) ? __expf(scL[i]) : 0.f;
      float su = e;
      #pragma unroll
      for (int d = 1; d < 64; d <<= 1) su += __shfl_xor(su, d);
      if ((i & 63) == 0) part[i >> 6] = su;
      __syncthreads();
      float S = (part[0] + part[1]) + (part[2] + part[3]);
      if (i < 256) wts[i] = e / S;
    }
    __syncthreads();
    // ---- ctx[i] = sum_s wts[s] * enc_outs[b][s][i] ----
    {
      const u16* eo = enc_outs + (size_t)b * 256 * 512 + i;
      float c0=0.f, c1=0.f, c2=0.f, c3=0.f;
      for (int s = 0; s < 256; s += 4) {
        c0 = fmaf(wts[s    ], bf2f(eo[(size_t)(s    ) * 512]), c0);
        c1 = fmaf(wts[s + 1], bf2f(eo[(size_t)(s + 1) * 512]), c1);
        c2 = fmaf(wts[s + 2], bf2f(eo[(size_t)(s + 2) * 512]), c2);
        c3 = fmaf(wts[s + 3], bf2f(eo[(size_t)(s + 3) * 512]), c3);
      }
      ctx[i] = (c0 + c1) + (c2 + c3);
    }
    __syncthreads();
    // ---- P3: GRU cell ----
    {
      float hR=0.f,hZ=0.f,hN=0.f,cR=0.f,cZ=0.f,cN=0.f;
      for (int k4 = 0; k4 < 128; ++k4) {
        float4 hv = *(const float4*)&hc[k4 * 4];
        float4 cv = *(const float4*)&ctx[k4 * 4];
        hR = dot4(hR, wht[(size_t)k4 * G3 + i],        hv);
        hZ = dot4(hZ, wht[(size_t)k4 * G3 + 512 + i],  hv);
        hN = dot4(hN, wht[(size_t)k4 * G3 + 1024 + i], hv);
        cR = dot4(cR, wit[(size_t)k4 * G3 + i],        cv);
        cZ = dot4(cZ, wit[(size_t)k4 * G3 + 512 + i],  cv);
        cN = dot4(cN, wit[(size_t)k4 * G3 + 1024 + i], cv);
      }
      const size_t g = ((size_t)t * 32 + b) * G3;
      float r = sigf (bf2f(gi[g +        i]) + cR + hR + bR);
      float z = sigf (bf2f(gi[g +  512 + i]) + cZ + hZ + bZ);
      float n = tanh_(bf2f(gi[g + 1024 + i]) + cN + r * (hN + bN));
      float h2 = z * hc[i] + (1.f - z) * n;
      h[(t + 1) & 1][i] = h2;
      h2bf[((size_t)t * 32 + b) * 512 + i] = f2bf(h2);
    }
    __syncthreads();
  }
}

// ---------- K5: logits via bf16 MFMA: out = h2 @ fcW^T + fc_b ----------
// Block: 64r x 64v tile; 4 waves, wave w owns 16 v-rows, loops 4 m-subtiles.
// A staged in LDS (granule-XOR swizzle); B converted f32->bf16 in-register.
__global__ __launch_bounds__(256)
void k_logits_mfma(const u16* __restrict__ A, const float* __restrict__ W,
                   const float* __restrict__ bias, float* __restrict__ out)
{
  __shared__ u16 Al[64 * 512];    // 64 KB
  const int tid = threadIdx.x;
  const int r0 = blockIdx.x * 64;
  const int v0 = blockIdx.y * 64;
  // stage A (4096 uint4), swizzled: granule g -> g ^ (row&7)
  {
    const uint4* src = (const uint4*)(A + (size_t)r0 * 512);
    uint4* dst = (uint4*)Al;
    #pragma unroll
    for (int j = 0; j < 16; ++j) {
      int idx = j * 256 + tid;
      int row = idx >> 6, g = idx & 63;
      dst[(row << 6) | (g ^ (row & 7))] = src[idx];
    }
  }
  const int w  = tid >> 6, l = tid & 63;
  const int lr = l & 15,  qk = l >> 4;
  const int v  = v0 + w * 16 + lr;
  // B frags: 16 k-chunks of this lane's weight row, f32 -> bf16
  frag bfr[16];
  {
    const float* wrow = W + (size_t)v * 512 + qk * 8;
    #pragma unroll
    for (int ks = 0; ks < 16; ++ks) {
      float4 w0 = *(const float4*)(wrow + ks * 32);
      float4 w1 = *(const float4*)(wrow + ks * 32 + 4);
      union { frag f; u16 s[8]; } u;
      u.s[0]=f2bf(w0.x); u.s[1]=f2bf(w0.y); u.s[2]=f2bf(w0.z); u.s[3]=f2bf(w0.w);
      u.s[4]=f2bf(w1.x); u.s[5]=f2bf(w1.y); u.s[6]=f2bf(w1.z); u.s[7]=f2bf(w1.w);
      bfr[ks] = u.f;
    }
  }
  const float bv = bias[v];
  __syncthreads();
  f32x4v acc[4];
  #pragma unroll
  for (int mt = 0; mt < 4; ++mt) acc[mt] = (f32x4v){0.f, 0.f, 0.f, 0.f};
  #pragma unroll
  for (int ks = 0; ks < 16; ++ks) {
    #pragma unroll
    for (int mt = 0; mt < 4; ++mt) {
      const int row = mt * 16 + lr;              // A row (M) = l&15
      const int gr  = ks * 4 + qk;               // A k-granule = (l>>4) quarter
      frag a = *(const frag*)&Al[(row << 9) | ((gr ^ (row & 7)) << 3)];
      acc[mt] = __builtin_amdgcn_mfma_f32_16x16x32_bf16(a, bfr[ks], acc[mt], 0, 0, 0);
    }
  }
  // C/D: col = l&15 (our v), row = (l>>4)*4 + reg (M within subtile)
  #pragma unroll
  for (int mt = 0; mt < 4; ++mt)
    #pragma unroll
    for (int reg = 0; reg < 4; ++reg) {
      const int r = r0 + mt * 16 + qk * 4 + reg;         // r = t*32 + b
      out[(size_t)(r & 31) * 64 * VV + (size_t)(r >> 5) * VV + v] = acc[mt][reg] + bv;
    }
}

// ---------- launch ----------
extern "C" void kernel_launch(void* const* d_in, const int* in_sizes, int n_in,
                              void* d_out, int out_size, void* d_ws, size_t ws_size,
                              hipStream_t stream) {
  (void)in_sizes; (void)n_in; (void)out_size; (void)ws_size;
  const int*   src  = (const int*)d_in[0];
  const int*   tgt  = (const int*)d_in[1];
  const float* eemb = (const float*)d_in[2];
  const float* eWih = (const float*)d_in[3];
  const float* eWhh = (const float*)d_in[4];
  const float* ebih = (const float*)d_in[5];
  const float* ebhh = (const float*)d_in[6];
  const float* demb = (const float*)d_in[7];
  const float* aW1  = (const float*)d_in[8];
  const float* ab1  = (const float*)d_in[9];
  const float* aW2  = (const float*)d_in[10];
  const float* ab2  = (const float*)d_in[11];
  const float* av   = (const float*)d_in[12];
  const float* dWih = (const float*)d_in[13];
  const float* dWhh = (const float*)d_in[14];
  const float* dbih = (const float*)d_in[15];
  const float* dbhh = (const float*)d_in[16];
  const float* fcW  = (const float*)d_in[17];
  const float* fcb  = (const float*)d_in[18];
  float* out = (float*)d_out;

  // workspace carve (~61 MiB)
  float* hT      = (float*)d_ws;                 //    16,384 f32
  float* eWt     = hT + 16384;                   //   786,432 f32
  float* dWht    = eWt + 786432;                 //   786,432 f32
  float* dWit    = dWht + 786432;                //   786,432 f32
  float* dW1t    = dWit + 786432;                //   262,144 f32
  u16*  h2bf     = (u16*)(dW1t + 262144);        // 1,048,576 u16
  u16*  gi_enc   = h2bf + 1048576;               // 12,582,912 u16
  u16*  gi_dec   = gi_enc + 12582912;            //  3,145,728 u16
  u16*  enc_outs = gi_dec + 3145728;             //  4,194,304 u16
  u16*  enc_proj = enc_outs + 4194304;           //  4,194,304 u16

  // weight transposes (one-time)
  k_wt<<<768, 256, 0, stream>>>(eWhh, eWt,  G3, 512, 0);
  k_wt<<<768, 256, 0, stream>>>(dWhh, dWht, G3, 512, 0);
  k_wt<<<768, 256, 0, stream>>>(dWih, dWit, G3, 768, 256);
  k_wt<<<256, 256, 0, stream>>>(aW1,  dW1t, HH, 512, 0);

  k_embed_gemm<<<dim3(6, 512), 256, 0, stream>>>(src, SS, eemb, eWih, EE,  ebih, gi_enc);
  k_embed_gemm<<<dim3(6, 128), 256, 0, stream>>>(tgt, TT, demb, dWih, 768, dbih, gi_dec);

  k_enc_scan_pb<<<32, 512, 0, stream>>>(gi_enc, eWt, ebhh, enc_outs, hT);

  k_proj<<<dim3(2, 512), 256, 0, stream>>>(enc_outs, aW2, ab2, enc_proj);

  k_dec_scan_pb<<<32, 512, 0, stream>>>(gi_dec, hT, dW1t, ab1, av,
                                        enc_proj, enc_outs, dWht, dWit, dbhh, h2bf);

  k_logits_mfma<<<dim3(32, 500), 256, 0, stream>>>(h2bf, fcW, fcb, out);
}

// Round 9
// 6779.720 us; speedup vs baseline: 1.9029x; 1.9029x over previous
//
#include <hip/hip_runtime.h>
#include <hip/hip_bf16.h>
#include <stdint.h>

#define DEV __device__ __forceinline__
typedef unsigned short u16;
typedef unsigned int   u32;
typedef unsigned long long u64;

static constexpr int SS = 256;   // src len
static constexpr int TT = 64;    // tgt len
static constexpr int EE = 256;   // embed dim
static constexpr int HH = 512;   // hidden
static constexpr int G3 = 1536;  // 3*H
static constexpr int VV = 32000; // vocab
static constexpr int HP = 516;   // padded f32 LDS row
static constexpr int CP = 528;   // padded u16 LDS row

using frag   = __attribute__((ext_vector_type(8))) short;  // 8 bf16
using f32x4v = __attribute__((ext_vector_type(4))) float;  // MFMA acc

// ---------- helpers ----------
DEV float blo(u32 u){ union{u32 i; float f;} x; x.i = u << 16;         return x.f; }
DEV float bhi(u32 u){ union{u32 i; float f;} x; x.i = u & 0xffff0000u; return x.f; }
DEV float bf2f(u16 u){ union{u32 i; float f;} x; x.i = ((u32)u) << 16; return x.f; }
DEV u16 f2bf(float f){ union{float f; u32 u;} v; v.f = f;
  u32 r = v.u + 0x7fffu + ((v.u >> 16) & 1u); return (u16)(r >> 16); }
DEV float sigf (float x){ return 1.0f / (1.0f + __expf(-x)); }
DEV float tanh_(float x){ return 1.0f - 2.0f / (1.0f + __expf(2.0f * x)); }
DEV void unp8(float* d, uint4 u){
  d[0]=blo(u.x); d[1]=bhi(u.x); d[2]=blo(u.y); d[3]=bhi(u.y);
  d[4]=blo(u.z); d[5]=bhi(u.z); d[6]=blo(u.w); d[7]=bhi(u.w);
}
DEV float dot4(float acc, float4 w, float4 x){
  acc = fmaf(w.x,x.x,acc); acc = fmaf(w.y,x.y,acc);
  acc = fmaf(w.z,x.z,acc); acc = fmaf(w.w,x.w,acc);
  return acc;
}
DEV float fma8(float acc, const float* w, float4 a, float4 b){
  acc = fmaf(w[0],a.x,acc); acc = fmaf(w[1],a.y,acc);
  acc = fmaf(w[2],a.z,acc); acc = fmaf(w[3],a.w,acc);
  acc = fmaf(w[4],b.x,acc); acc = fmaf(w[5],b.y,acc);
  acc = fmaf(w[6],b.z,acc); acc = fmaf(w[7],b.w,acc);
  return acc;
}
DEV float fma8p(float acc, const float* w, const float* x){
  #pragma unroll
  for (int e = 0; e < 8; ++e) acc = fmaf(w[e], x[e], acc);
  return acc;
}

// ---- coherent (agent-scope) accessors: write-through, cache-bypassing ----
DEV void  ast_f (float* p, float v){ __hip_atomic_store(p, v, __ATOMIC_RELAXED, __HIP_MEMORY_SCOPE_AGENT); }
DEV void  ast_u (u32* p, u32 v)    { __hip_atomic_store(p, v, __ATOMIC_RELAXED, __HIP_MEMORY_SCOPE_AGENT); }
DEV float ald_f (const float* p)   { return __hip_atomic_load((float*)p, __ATOMIC_RELAXED, __HIP_MEMORY_SCOPE_AGENT); }
DEV u64   ald_u8(const u64* p)     { return __hip_atomic_load((u64*)p,   __ATOMIC_RELAXED, __HIP_MEMORY_SCOPE_AGENT); }

// fence-free grid barrier (proven round 7). All exchanged data uses
// agent-scope atomics; __syncthreads drains stores before the counter RMW.
DEV void grid_bar(u32* cnt, u32 target){
  __syncthreads();
  if (threadIdx.x == 0) {
    __hip_atomic_fetch_add(cnt, 1u, __ATOMIC_RELAXED, __HIP_MEMORY_SCOPE_AGENT);
    while (__hip_atomic_load(cnt, __ATOMIC_RELAXED, __HIP_MEMORY_SCOPE_AGENT) < target)
      __builtin_amdgcn_s_sleep(1);
  }
  __syncthreads();
}

// ---------- K1: gi = gather(emb, tok) @ W[:, :256]^T + bih  (bf16 out) ----
__global__ __launch_bounds__(256)
void k_embed_gemm(const int* __restrict__ tok, int Tlen,
                  const float* __restrict__ emb,
                  const float* __restrict__ W, int wstride,
                  const float* __restrict__ bias,
                  u16* __restrict__ gi)
{
  __shared__ float es[16][EE];
  const int tid = threadIdx.x;
  const int r0 = blockIdx.y * 16;
  #pragma unroll
  for (int rr = 0; rr < 16; ++rr) {
    int r = r0 + rr;
    int token = tok[(r & 31) * Tlen + (r >> 5)];
    es[rr][tid] = emb[(size_t)token * EE + tid];
  }
  __syncthreads();
  const int jl = tid & 63;
  const int rg = (tid >> 6) << 2;
  const int jbase = blockIdx.x * 256 + jl;
  float acc[4][4];
  #pragma unroll
  for (int jj = 0; jj < 4; ++jj) {
    float bv = bias[jbase + jj * 64];
    #pragma unroll
    for (int rr = 0; rr < 4; ++rr) acc[jj][rr] = bv;
  }
  const float4* w0 = (const float4*)(W + (size_t)(jbase      ) * wstride);
  const float4* w1 = (const float4*)(W + (size_t)(jbase +  64) * wstride);
  const float4* w2 = (const float4*)(W + (size_t)(jbase + 128) * wstride);
  const float4* w3 = (const float4*)(W + (size_t)(jbase + 192) * wstride);
  for (int k4 = 0; k4 < EE / 4; ++k4) {
    float4 wv0 = w0[k4], wv1 = w1[k4], wv2 = w2[k4], wv3 = w3[k4];
    #pragma unroll
    for (int rr = 0; rr < 4; ++rr) {
      float4 e = *(const float4*)&es[rg + rr][k4 * 4];
      acc[0][rr] = dot4(acc[0][rr], wv0, e);
      acc[1][rr] = dot4(acc[1][rr], wv1, e);
      acc[2][rr] = dot4(acc[2][rr], wv2, e);
      acc[3][rr] = dot4(acc[3][rr], wv3, e);
    }
  }
  #pragma unroll
  for (int rr = 0; rr < 4; ++rr)
    #pragma unroll
    for (int jj = 0; jj < 4; ++jj)
      gi[(size_t)(r0 + rg + rr) * G3 + jbase + jj * 64] = f2bf(acc[jj][rr]);
}

// ---------- K2: encoder GRU scan — persistent, 128 blocks, 1 bar/step ----
// (round-7 kernel, proven) Block owns 4 i's x3 gates; weights in LDS (bf16).
__global__ __launch_bounds__(256)
void k_enc_scan(const u16* __restrict__ gi, const float* __restrict__ Whh,
                const float* __restrict__ bhh, u16* __restrict__ hbufE,
                u16* __restrict__ enc_outs, u32* __restrict__ bar)
{
  __shared__ float hs[32 * HP];   // 66 KB
  __shared__ u16  wsl[12 * 512];  // 12 KB
  __shared__ float h2t[4][32];
  const int tid = threadIdx.x;
  const int bid = blockIdx.x;
  const int i0 = bid * 4;
  #pragma unroll
  for (int j = 0; j < 6; ++j) {   // stage 12 weight rows once (f32 -> bf16)
    int f = (j * 256 + tid) * 4;
    int g = f >> 11, r = f & 2047;
    int row = g * 512 + i0 + (r >> 9), k = r & 511;
    float4 w = *(const float4*)(Whh + (size_t)row * 512 + k);
    wsl[f] = f2bf(w.x); wsl[f+1] = f2bf(w.y); wsl[f+2] = f2bf(w.z); wsl[f+3] = f2bf(w.w);
  }
  const int i_l = tid >> 6, lane = tid & 63, b = lane >> 1, kh = lane & 1;
  const int i = i0 + i_l;
  const u16* w0 = wsl + (0 * 4 + i_l) * 512 + kh * 256;
  const u16* w1 = wsl + (1 * 4 + i_l) * 512 + kh * 256;
  const u16* w2 = wsl + (2 * 4 + i_l) * 512 + kh * 256;
  const float bR = bhh[i], bZ = bhh[i + 512], bN = bhh[i + 1024];
  u32 bt = 0;
  for (int t = 0; t < SS; ++t) {
    const u64* hsrc = (const u64*)(hbufE + (t & 1) * 16384);
    #pragma unroll
    for (int j = 0; j < 16; ++j) {
      int idx = j * 256 + tid;
      u64 v = ald_u8(hsrc + idx);
      int bb = idx >> 7, m = (idx & 127) * 4;
      *(float4*)&hs[bb * HP + m] = make_float4(
        bf2f((u16)v), bf2f((u16)(v >> 16)), bf2f((u16)(v >> 32)), bf2f((u16)(v >> 48)));
    }
    __syncthreads();
    float aR = 0.f, aZ = 0.f, aN = 0.f;
    const float* hb = hs + b * HP + kh * 256;
    for (int k8 = 0; k8 < 32; ++k8) {
      float4 h0 = *(const float4*)&hb[k8*8], h1 = *(const float4*)&hb[k8*8+4];
      float wf[8];
      unp8(wf, *(const uint4*)(w0 + k8 * 8)); aR = fma8(aR, wf, h0, h1);
      unp8(wf, *(const uint4*)(w1 + k8 * 8)); aZ = fma8(aZ, wf, h0, h1);
      unp8(wf, *(const uint4*)(w2 + k8 * 8)); aN = fma8(aN, wf, h0, h1);
    }
    aR += __shfl_xor(aR, 1);
    aZ += __shfl_xor(aZ, 1);
    aN += __shfl_xor(aN, 1);
    if (kh == 0) {
      const size_t g = ((size_t)t * 32 + b) * G3;
      float r = sigf (bf2f(gi[g +        i]) + aR + bR);
      float z = sigf (bf2f(gi[g +  512 + i]) + aZ + bZ);
      float n = tanh_(bf2f(gi[g + 1024 + i]) + r * (aN + bN));
      float h2 = z * hs[b * HP + i] + (1.f - z) * n;
      enc_outs[((size_t)b * 256 + t) * 512 + i] = f2bf(h2);
      h2t[i_l][b] = h2;
    }
    __syncthreads();
    if (tid < 64) {
      int p = tid >> 5, bq = tid & 31;
      u32 pk = (u32)f2bf(h2t[2*p][bq]) | ((u32)f2bf(h2t[2*p+1][bq]) << 16);
      ast_u((u32*)(hbufE + ((t + 1) & 1) * 16384) + bq * 256 + bid * 2 + p, pk);
    }
    bt += 128; grid_bar(bar, bt);
  }
}

// ---------- K3: enc_proj = enc_outs @ attn_W2^T + b2 ----------
__global__ __launch_bounds__(256)
void k_proj(const u16* __restrict__ A, const float* __restrict__ W,
            const float* __restrict__ bias, u16* __restrict__ Out)
{
  __shared__ float es[16][HH];
  const int tid = threadIdx.x;
  const int r0 = blockIdx.y * 16;
  #pragma unroll
  for (int j = 0; j < 4; ++j) {
    int u = j * 256 + tid;
    int row = u >> 6, k = (u & 63) * 8;
    float d[8]; unp8(d, *(const uint4*)(A + (size_t)(r0 + row) * HH + k));
    *(float4*)&es[row][k]     = make_float4(d[0],d[1],d[2],d[3]);
    *(float4*)&es[row][k + 4] = make_float4(d[4],d[5],d[6],d[7]);
  }
  __syncthreads();
  const int jl = tid & 63;
  const int rg = (tid >> 6) << 2;
  const int jbase = blockIdx.x * 256 + jl;
  float acc[4][4];
  #pragma unroll
  for (int jj = 0; jj < 4; ++jj) {
    float bv = bias[jbase + jj * 64];
    #pragma unroll
    for (int rr = 0; rr < 4; ++rr) acc[jj][rr] = bv;
  }
  const float4* w0 = (const float4*)(W + (size_t)(jbase      ) * HH);
  const float4* w1 = (const float4*)(W + (size_t)(jbase +  64) * HH);
  const float4* w2 = (const float4*)(W + (size_t)(jbase + 128) * HH);
  const float4* w3 = (const float4*)(W + (size_t)(jbase + 192) * HH);
  for (int k4 = 0; k4 < HH / 4; ++k4) {
    float4 wv0 = w0[k4], wv1 = w1[k4], wv2 = w2[k4], wv3 = w3[k4];
    #pragma unroll
    for (int rr = 0; rr < 4; ++rr) {
      float4 e = *(const float4*)&es[rg + rr][k4 * 4];
      acc[0][rr] = dot4(acc[0][rr], wv0, e);
      acc[1][rr] = dot4(acc[1][rr], wv1, e);
      acc[2][rr] = dot4(acc[2][rr], wv2, e);
      acc[3][rr] = dot4(acc[3][rr], wv3, e);
    }
  }
  #pragma unroll
  for (int rr = 0; rr < 4; ++rr)
    #pragma unroll
    for (int jj = 0; jj < 4; ++jj)
      Out[(size_t)(r0 + rg + rr) * HH + jbase + jj * 64] = f2bf(acc[jj][rr]);
}

// ---------- K4: decoder scan — persistent, 128 blocks, 3 bars/step -------
// Round-7 structure + ALL 28 weight rows/block staged once to LDS as bf16
// (4 W1 + 12 Whh + 12 Wih-ctx). ctx staged to LDS as bf16. No-max softmax.
__global__ __launch_bounds__(256)
void k_dec_scan(const u16* __restrict__ gi, u16* __restrict__ hbufE,
                const float* __restrict__ W1, const float* __restrict__ b1,
                const float* __restrict__ av,
                const u16* __restrict__ enc_proj, const u16* __restrict__ enc_outs,
                const float* __restrict__ Whh, const float* __restrict__ Wih,
                const float* __restrict__ bhh,
                float* __restrict__ a_buf, float* __restrict__ ctxacc,
                float* __restrict__ S_acc, u16* __restrict__ h2bf,
                u32* __restrict__ bar)
{
  __shared__ float hs[32 * HP];     // 66.0 KB
  __shared__ u16  csb[32 * CP];     // 33.8 KB (bf16 ctx)
  __shared__ u16  wlds[28 * 512];   // 28.7 KB (bf16 weights, persistent)
  __shared__ float as_[512], vs_[512];
  __shared__ float scq[4][64], wts[64];
  __shared__ float rs[32];
  __shared__ float h2t[4][32];
  const int tid = threadIdx.x;
  const int bid = blockIdx.x;
  const int i_l = tid >> 6, lane = tid & 63, b = lane >> 1, kh = lane & 1;
  const int i0 = bid * 4;
  const int i = i0 + i_l;
  const int pb = bid >> 2, sq = bid & 3;
  vs_[tid] = av[tid]; vs_[tid + 256] = av[tid + 256];
  // stage 28 weight rows once: 3584 float4 = 14/thread
  #pragma unroll
  for (int j = 0; j < 14; ++j) {
    int idx = j * 256 + tid;
    int row = idx >> 7, k4 = idx & 127;
    const float* src;
    if (row < 4)        src = W1  + (size_t)(i0 + row) * 512 + k4 * 4;
    else if (row < 16) { int rr = row - 4;
                         src = Whh + (size_t)((rr >> 2) * 512 + i0 + (rr & 3)) * 512 + k4 * 4; }
    else               { int rr = row - 16;
                         src = Wih + (size_t)((rr >> 2) * 512 + i0 + (rr & 3)) * 768 + 256 + k4 * 4; }
    float4 w = *(const float4*)src;
    int f = row * 512 + k4 * 4;
    wlds[f] = f2bf(w.x); wlds[f+1] = f2bf(w.y); wlds[f+2] = f2bf(w.z); wlds[f+3] = f2bf(w.w);
  }
  const u16* w1r = wlds + (     i_l) * 512 + kh * 256;
  const u16* whr = wlds + ( 4 + i_l) * 512 + kh * 256;
  const u16* whz = wlds + ( 8 + i_l) * 512 + kh * 256;
  const u16* whn = wlds + (12 + i_l) * 512 + kh * 256;
  const u16* wir = wlds + (16 + i_l) * 512 + kh * 256;
  const u16* wiz = wlds + (20 + i_l) * 512 + kh * 256;
  const u16* win = wlds + (24 + i_l) * 512 + kh * 256;
  const float bR = bhh[i], bZ = bhh[i + 512], bN = bhh[i + 1024];
  const float b1i = b1[i];
  u32 bt = 0;
  for (int t = 0; t < TT; ++t) {
    // stage h (coherent u64 loads)
    const u64* hsrc = (const u64*)(hbufE + (t & 1) * 16384);
    #pragma unroll
    for (int j = 0; j < 16; ++j) {
      int idx = j * 256 + tid;
      u64 v = ald_u8(hsrc + idx);
      int bb = idx >> 7, m = (idx & 127) * 4;
      *(float4*)&hs[bb * HP + m] = make_float4(
        bf2f((u16)v), bf2f((u16)(v >> 16)), bf2f((u16)(v >> 32)), bf2f((u16)(v >> 48)));
    }
    // zero this step's accumulators (P1 window)
    if (bid < 32) {
      ast_f(&ctxacc[bid * 512 + tid],       0.f);
      ast_f(&ctxacc[bid * 512 + 256 + tid], 0.f);
      if (tid == 0) ast_f(&S_acc[bid], 0.f);
    }
    __syncthreads();
    // ---- P1: a[b,i] = b1[i] + h . W1[i,:]  (LDS weights) ----
    {
      const float* hb = hs + b * HP + kh * 256;
      float acc = 0.f;
      for (int k8 = 0; k8 < 32; ++k8) {
        float wf[8]; unp8(wf, *(const uint4*)(w1r + k8 * 8));
        acc = fma8(acc, wf, *(const float4*)&hb[k8*8], *(const float4*)&hb[k8*8+4]);
      }
      acc += __shfl_xor(acc, 1);
      if (kh == 0) ast_f(&a_buf[b * 512 + i], acc + b1i);
    }
    bt += 128; grid_bar(bar, bt);
    // ---- P2: scores -> exp -> partial ctx/S atomicAdd (block=(pb,sq)) ----
    {
      u64 v = ald_u8((const u64*)(a_buf + pb * 512) + tid);
      union { u64 q; float f[2]; } cv; cv.q = v;
      as_[2 * tid] = cv.f[0]; as_[2 * tid + 1] = cv.f[1];
    }
    __syncthreads();
    {
      const int kp = tid >> 6, s_l = tid & 63;
      const int s = sq * 64 + s_l;
      const u16* pr = enc_proj + ((size_t)pb * 256 + s) * 512 + kp * 128;
      const float* ak = as_ + kp * 128;
      const float* vk = vs_ + kp * 128;
      float acc = 0.f;
      for (int k8 = 0; k8 < 16; ++k8) {
        float d[8]; unp8(d, *(const uint4*)(pr + k8 * 8));
        #pragma unroll
        for (int e = 0; e < 8; ++e)
          acc += vk[k8 * 8 + e] * tanh_(d[e] + ak[k8 * 8 + e]);
      }
      scq[kp][s_l] = acc;
    }
    __syncthreads();
    if (tid < 64) {
      float sc = (scq[0][tid] + scq[1][tid]) + (scq[2][tid] + scq[3][tid]);
      float e = __expf(sc);          // bounded scores: no max-shift
      wts[tid] = e;
      float su = e;
      #pragma unroll
      for (int d = 1; d < 64; d <<= 1) su += __shfl_xor(su, d);
      if (tid == 0) atomicAdd(&S_acc[pb], su);
    }
    __syncthreads();
    {
      const int k0 = tid * 2;
      float c0 = 0.f, c1 = 0.f;
      const u16* eo = enc_outs + ((size_t)pb * 256 + sq * 64) * 512 + k0;
      for (int s = 0; s < 64; ++s) {
        float w = wts[s];
        u32 pair = *(const u32*)(eo + (size_t)s * 512);
        c0 = fmaf(w, blo(pair), c0);
        c1 = fmaf(w, bhi(pair), c1);
      }
      atomicAdd(&ctxacc[pb * 512 + k0],     c0);
      atomicAdd(&ctxacc[pb * 512 + k0 + 1], c1);
    }
    bt += 128; grid_bar(bar, bt);
    // ---- P3: normalize ctx -> bf16 LDS, GRU cell (LDS weights) ----
    if (tid < 32) rs[tid] = 1.f / ald_f(&S_acc[tid]);
    __syncthreads();
    #pragma unroll
    for (int j = 0; j < 32; ++j) {
      int idx = j * 256 + tid;           // 8192 u64 = 16384 f32
      u64 v = ald_u8((const u64*)ctxacc + idx);
      union { u64 q; float f[2]; } cv; cv.q = v;
      int bb = idx >> 8, m = (idx & 255) * 2;
      float r = rs[bb];
      *(u32*)&csb[bb * CP + m] =
        (u32)f2bf(cv.f[0] * r) | ((u32)f2bf(cv.f[1] * r) << 16);
    }
    __syncthreads();
    {
      const float* hb = hs + b * HP + kh * 256;
      const u16*   cb = csb + b * CP + kh * 256;
      float hR=0.f,hZ=0.f,hN=0.f,cR=0.f,cZ=0.f,cN=0.f;
      for (int k8 = 0; k8 < 32; ++k8) {
        float4 h0 = *(const float4*)&hb[k8*8], h1 = *(const float4*)&hb[k8*8+4];
        float cf[8]; unp8(cf, *(const uint4*)(cb + k8 * 8));
        float wf[8];
        unp8(wf, *(const uint4*)(whr + k8 * 8)); hR = fma8(hR, wf, h0, h1);
        unp8(wf, *(const uint4*)(whz + k8 * 8)); hZ = fma8(hZ, wf, h0, h1);
        unp8(wf, *(const uint4*)(whn + k8 * 8)); hN = fma8(hN, wf, h0, h1);
        unp8(wf, *(const uint4*)(wir + k8 * 8)); cR = fma8p(cR, wf, cf);
        unp8(wf, *(const uint4*)(wiz + k8 * 8)); cZ = fma8p(cZ, wf, cf);
        unp8(wf, *(const uint4*)(win + k8 * 8)); cN = fma8p(cN, wf, cf);
      }
      hR += __shfl_xor(hR, 1); hZ += __shfl_xor(hZ, 1); hN += __shfl_xor(hN, 1);
      cR += __shfl_xor(cR, 1); cZ += __shfl_xor(cZ, 1); cN += __shfl_xor(cN, 1);
      if (kh == 0) {
        const size_t g = ((size_t)t * 32 + b) * G3;
        float r = sigf (bf2f(gi[g +        i]) + cR + hR + bR);
        float z = sigf (bf2f(gi[g +  512 + i]) + cZ + hZ + bZ);
        float n = tanh_(bf2f(gi[g + 1024 + i]) + cN + r * (hN + bN));
        float h2 = z * hs[b * HP + i] + (1.f - z) * n;
        h2bf[((size_t)t * 32 + b) * 512 + i] = f2bf(h2);
        h2t[i_l][b] = h2;
      }
    }
    __syncthreads();
    if (tid < 64) {
      int p = tid >> 5, bq = tid & 31;
      u32 pk = (u32)f2bf(h2t[2*p][bq]) | ((u32)f2bf(h2t[2*p+1][bq]) << 16);
      ast_u((u32*)(hbufE + ((t + 1) & 1) * 16384) + bq * 256 + bid * 2 + p, pk);
    }
    bt += 128; grid_bar(bar, bt);
  }
}

// ---------- K5: fcW f32 -> bf16 (one-time) ----------
__global__ __launch_bounds__(256)
void k_cvt(const float* __restrict__ in, u16* __restrict__ out)
{
  size_t i = ((size_t)blockIdx.x * 256 + threadIdx.x) * 8;
  float4 a = *(const float4*)(in + i);
  float4 b = *(const float4*)(in + i + 4);
  union { uint4 v; u16 s[8]; } u;
  u.s[0]=f2bf(a.x); u.s[1]=f2bf(a.y); u.s[2]=f2bf(a.z); u.s[3]=f2bf(a.w);
  u.s[4]=f2bf(b.x); u.s[5]=f2bf(b.y); u.s[6]=f2bf(b.z); u.s[7]=f2bf(b.w);
  *(uint4*)(out + i) = u.v;
}

// ---------- K6: logits via bf16 MFMA (round-8 kernel, bf16 W input) ------
__global__ __launch_bounds__(256)
void k_logits_mfma(const u16* __restrict__ A, const u16* __restrict__ Wb,
                   const float* __restrict__ bias, float* __restrict__ out)
{
  __shared__ u16 Al[64 * 512];    // 64 KB
  const int tid = threadIdx.x;
  const int r0 = blockIdx.x * 64;
  const int v0 = blockIdx.y * 64;
  {
    const uint4* src = (const uint4*)(A + (size_t)r0 * 512);
    uint4* dst = (uint4*)Al;
    #pragma unroll
    for (int j = 0; j < 16; ++j) {
      int idx = j * 256 + tid;
      int row = idx >> 6, g = idx & 63;
      dst[(row << 6) | (g ^ (row & 7))] = src[idx];
    }
  }
  const int w  = tid >> 6, l = tid & 63;
  const int lr = l & 15,  qk = l >> 4;
  const int v  = v0 + w * 16 + lr;
  frag bfr[16];
  {
    const u16* wrow = Wb + (size_t)v * 512 + qk * 8;
    #pragma unroll
    for (int ks = 0; ks < 16; ++ks)
      bfr[ks] = *(const frag*)(wrow + ks * 32);
  }
  const float bv = bias[v];
  __syncthreads();
  f32x4v acc[4];
  #pragma unroll
  for (int mt = 0; mt < 4; ++mt) acc[mt] = (f32x4v){0.f, 0.f, 0.f, 0.f};
  #pragma unroll
  for (int ks = 0; ks < 16; ++ks) {
    #pragma unroll
    for (int mt = 0; mt < 4; ++mt) {
      const int row = mt * 16 + lr;
      const int gr  = ks * 4 + qk;
      frag a = *(const frag*)&Al[(row << 9) | ((gr ^ (row & 7)) << 3)];
      acc[mt] = __builtin_amdgcn_mfma_f32_16x16x32_bf16(a, bfr[ks], acc[mt], 0, 0, 0);
    }
  }
  #pragma unroll
  for (int mt = 0; mt < 4; ++mt)
    #pragma unroll
    for (int reg = 0; reg < 4; ++reg) {
      const int r = r0 + mt * 16 + qk * 4 + reg;         // r = t*32 + b
      out[(size_t)(r & 31) * 64 * VV + (size_t)(r >> 5) * VV + v] = acc[mt][reg] + bv;
    }
}

// ---------- launch ----------
extern "C" void kernel_launch(void* const* d_in, const int* in_sizes, int n_in,
                              void* d_out, int out_size, void* d_ws, size_t ws_size,
                              hipStream_t stream) {
  (void)in_sizes; (void)n_in; (void)out_size; (void)ws_size;
  const int*   src  = (const int*)d_in[0];
  const int*   tgt  = (const int*)d_in[1];
  const float* eemb = (const float*)d_in[2];
  const float* eWih = (const float*)d_in[3];
  const float* eWhh = (const float*)d_in[4];
  const float* ebih = (const float*)d_in[5];
  const float* ebhh = (const float*)d_in[6];
  const float* demb = (const float*)d_in[7];
  const float* aW1  = (const float*)d_in[8];
  const float* ab1  = (const float*)d_in[9];
  const float* aW2  = (const float*)d_in[10];
  const float* ab2  = (const float*)d_in[11];
  const float* av   = (const float*)d_in[12];
  const float* dWih = (const float*)d_in[13];
  const float* dWhh = (const float*)d_in[14];
  const float* dbih = (const float*)d_in[15];
  const float* dbhh = (const float*)d_in[16];
  const float* fcW  = (const float*)d_in[17];
  const float* fcb  = (const float*)d_in[18];
  float* out = (float*)d_out;

  // workspace carve (~50 MiB)
  float* a_buf   = (float*)d_ws;                 //    16,384 f32
  float* ctxacc  = a_buf + 16384;                //    16,384 f32
  float* S_acc   = ctxacc + 16384;               //        32 f32
  u32*   bars    = (u32*)(S_acc + 32);           //         8 u32
  u16*  hbufE    = (u16*)(bars + 8);             //    32,768 u16
  u16*  h2bf     = hbufE + 32768;                // 1,048,576 u16
  u16*  gi_enc   = h2bf + 1048576;               // 12,582,912 u16
  u16*  gi_dec   = gi_enc + 12582912;            //  3,145,728 u16
  u16*  enc_outs = gi_dec + 3145728;             //  4,194,304 u16
  u16*  enc_proj = enc_outs + 4194304;           //  4,194,304 u16
  // wbf aliases gi_enc..enc_outs (all dead after k_dec_scan): 16,384,000 u16
  u16*  wbf      = gi_enc;

  hipMemsetAsync(hbufE, 0, 32768 * sizeof(u16), stream);           // h0 = 0
  hipMemsetAsync(ctxacc, 0, (16384 + 32) * sizeof(float), stream); // ctx/S
  hipMemsetAsync(bars, 0, 8 * sizeof(u32), stream);                // counters

  k_embed_gemm<<<dim3(6, 512), 256, 0, stream>>>(src, SS, eemb, eWih, EE,  ebih, gi_enc);
  k_embed_gemm<<<dim3(6, 128), 256, 0, stream>>>(tgt, TT, demb, dWih, 768, dbih, gi_dec);

  k_enc_scan<<<128, 256, 0, stream>>>(gi_enc, eWhh, ebhh, hbufE, enc_outs, bars + 0);

  k_proj<<<dim3(2, 512), 256, 0, stream>>>(enc_outs, aW2, ab2, enc_proj);

  k_dec_scan<<<128, 256, 0, stream>>>(gi_dec, hbufE, aW1, ab1, av,
                                      enc_proj, enc_outs, dWhh, dWih, dbhh,
                                      a_buf, ctxacc, S_acc, h2bf, bars + 1);

  k_cvt<<<8000, 256, 0, stream>>>(fcW, wbf);   // gi_* dead; reuse as bf16 fcW

  k_logits_mfma<<<dim3(32, 500), 256, 0, stream>>>(h2bf, wbf, fcb, out);
}

// Round 13
// 6351.447 us; speedup vs baseline: 2.0312x; 1.0674x over previous
//
#include <hip/hip_runtime.h>
#include <hip/hip_bf16.h>
#include <stdint.h>

#define DEV __device__ __forceinline__
typedef unsigned short u16;
typedef unsigned int   u32;
typedef unsigned long long u64;

static constexpr int SS = 256;   // src len
static constexpr int TT = 64;    // tgt len
static constexpr int EE = 256;   // embed dim
static constexpr int HH = 512;   // hidden
static constexpr int G3 = 1536;  // 3*H
static constexpr int VV = 32000; // vocab
static constexpr int HP = 516;   // padded f32 LDS row (4-way max)
static constexpr int CP = 520;   // padded u16 LDS row (4-way max)

using frag   = __attribute__((ext_vector_type(8))) short;  // 8 bf16
using f32x4v = __attribute__((ext_vector_type(4))) float;  // MFMA acc

// ---------- helpers ----------
DEV float blo(u32 u){ union{u32 i; float f;} x; x.i = u << 16;         return x.f; }
DEV float bhi(u32 u){ union{u32 i; float f;} x; x.i = u & 0xffff0000u; return x.f; }
DEV float bf2f(u16 u){ union{u32 i; float f;} x; x.i = ((u32)u) << 16; return x.f; }
DEV u16 f2bf(float f){ union{float f; u32 u;} v; v.f = f;
  u32 r = v.u + 0x7fffu + ((v.u >> 16) & 1u); return (u16)(r >> 16); }
DEV float sigf (float x){ return 1.0f / (1.0f + __expf(-x)); }
DEV float tanh_(float x){ return 1.0f - 2.0f / (1.0f + __expf(2.0f * x)); }
DEV void unp8(float* d, uint4 u){
  d[0]=blo(u.x); d[1]=bhi(u.x); d[2]=blo(u.y); d[3]=bhi(u.y);
  d[4]=blo(u.z); d[5]=bhi(u.z); d[6]=blo(u.w); d[7]=bhi(u.w);
}
DEV float dot4(float acc, float4 w, float4 x){
  acc = fmaf(w.x,x.x,acc); acc = fmaf(w.y,x.y,acc);
  acc = fmaf(w.z,x.z,acc); acc = fmaf(w.w,x.w,acc);
  return acc;
}
DEV float fma44(float acc, float4 w0, float4 w1, float4 h0, float4 h1){
  return dot4(dot4(acc, w0, h0), w1, h1);
}
DEV float fma8(float acc, const float* w, float4 a, float4 b){
  acc = fmaf(w[0],a.x,acc); acc = fmaf(w[1],a.y,acc);
  acc = fmaf(w[2],a.z,acc); acc = fmaf(w[3],a.w,acc);
  acc = fmaf(w[4],b.x,acc); acc = fmaf(w[5],b.y,acc);
  acc = fmaf(w[6],b.z,acc); acc = fmaf(w[7],b.w,acc);
  return acc;
}
DEV float fma8p(float acc, const float* w, const float* x){
  #pragma unroll
  for (int e = 0; e < 8; ++e) acc = fmaf(w[e], x[e], acc);
  return acc;
}

// ---- agent-scope atomic accessors ----
// COHERENCE RULE (established r9 green vs r10/r11/r12 identical-error reds):
// within a persistent kernel, cross-block data must be PRODUCED by agent-
// scope atomic stores AND CONSUMED by agent-scope atomic loads (L2-bypass).
// Plain loads are stale-prone even for write-once ring slots (suspected L2
// stream prefetch of sequential slots ahead of the producing write).
// Plain loads are safe only across kernel-launch boundaries.
DEV void  ast_f(float* p, float v){ __hip_atomic_store(p, v, __ATOMIC_RELAXED, __HIP_MEMORY_SCOPE_AGENT); }
DEV void  ast_u(u32* p, u32 v)    { __hip_atomic_store(p, v, __ATOMIC_RELAXED, __HIP_MEMORY_SCOPE_AGENT); }
DEV float ald_f(const float* p)   { return __hip_atomic_load((float*)p, __ATOMIC_RELAXED, __HIP_MEMORY_SCOPE_AGENT); }
DEV u64   ald_u8(const u64* p)    { return __hip_atomic_load((u64*)p,   __ATOMIC_RELAXED, __HIP_MEMORY_SCOPE_AGENT); }

// fence-free grid barrier (proven r7/r9).
DEV void grid_bar(u32* cnt, u32 target){
  __syncthreads();
  if (threadIdx.x == 0) {
    __hip_atomic_fetch_add(cnt, 1u, __ATOMIC_RELAXED, __HIP_MEMORY_SCOPE_AGENT);
    while (__hip_atomic_load(cnt, __ATOMIC_RELAXED, __HIP_MEMORY_SCOPE_AGENT) < target)
      __builtin_amdgcn_s_sleep(1);
  }
  __syncthreads();
}

// ---------- K1: gi = gather(emb, tok) @ W[:, :256]^T + bih  (bf16 out) ----
__global__ __launch_bounds__(256)
void k_embed_gemm(const int* __restrict__ tok, int Tlen,
                  const float* __restrict__ emb,
                  const float* __restrict__ W, int wstride,
                  const float* __restrict__ bias,
                  u16* __restrict__ gi)
{
  __shared__ float es[16][EE];
  const int tid = threadIdx.x;
  const int r0 = blockIdx.y * 16;
  #pragma unroll
  for (int rr = 0; rr < 16; ++rr) {
    int r = r0 + rr;
    int token = tok[(r & 31) * Tlen + (r >> 5)];
    es[rr][tid] = emb[(size_t)token * EE + tid];
  }
  __syncthreads();
  const int jl = tid & 63;
  const int rg = (tid >> 6) << 2;
  const int jbase = blockIdx.x * 256 + jl;
  float acc[4][4];
  #pragma unroll
  for (int jj = 0; jj < 4; ++jj) {
    float bv = bias[jbase + jj * 64];
    #pragma unroll
    for (int rr = 0; rr < 4; ++rr) acc[jj][rr] = bv;
  }
  const float4* w0 = (const float4*)(W + (size_t)(jbase      ) * wstride);
  const float4* w1 = (const float4*)(W + (size_t)(jbase +  64) * wstride);
  const float4* w2 = (const float4*)(W + (size_t)(jbase + 128) * wstride);
  const float4* w3 = (const float4*)(W + (size_t)(jbase + 192) * wstride);
  for (int k4 = 0; k4 < EE / 4; ++k4) {
    float4 wv0 = w0[k4], wv1 = w1[k4], wv2 = w2[k4], wv3 = w3[k4];
    #pragma unroll
    for (int rr = 0; rr < 4; ++rr) {
      float4 e = *(const float4*)&es[rg + rr][k4 * 4];
      acc[0][rr] = dot4(acc[0][rr], wv0, e);
      acc[1][rr] = dot4(acc[1][rr], wv1, e);
      acc[2][rr] = dot4(acc[2][rr], wv2, e);
      acc[3][rr] = dot4(acc[3][rr], wv3, e);
    }
  }
  #pragma unroll
  for (int rr = 0; rr < 4; ++rr)
    #pragma unroll
    for (int jj = 0; jj < 4; ++jj)
      gi[(size_t)(r0 + rg + rr) * G3 + jbase + jj * 64] = f2bf(acc[jj][rr]);
}

// ---------- K2: encoder GRU scan — persistent, 128 blocks, 1 bar/step ----
// h-carry ring slots: producers ast_u, consumers ATOMIC u64 loads (r9 rule).
__global__ __launch_bounds__(256)
void k_enc_scan(const u16* __restrict__ gi, const float* __restrict__ Whh,
                const float* __restrict__ bhh, u16* __restrict__ hring,
                u16* __restrict__ enc_outs, u32* __restrict__ bar)
{
  __shared__ float hs[32 * HP];    // 66.0 KB
  __shared__ float wsl[12 * 512];  // 24.0 KB f32 weights
  __shared__ float h2t[4][32];
  const int tid = threadIdx.x;
  const int bid = blockIdx.x;
  const int i0 = bid * 4;
  #pragma unroll
  for (int j = 0; j < 6; ++j) {    // stage 12 weight rows once (f32)
    int f = (j * 256 + tid) * 4;
    int g = f >> 11, r = f & 2047;
    int row = g * 512 + i0 + (r >> 9), k = r & 511;
    *(float4*)&wsl[f] = *(const float4*)(Whh + (size_t)row * 512 + k);
  }
  const int i_l = tid >> 6, lane = tid & 63, b = lane >> 1, kh = lane & 1;
  const int i = i0 + i_l;
  const float* w0 = wsl + (0 * 4 + i_l) * 512 + kh * 256;
  const float* w1 = wsl + (1 * 4 + i_l) * 512 + kh * 256;
  const float* w2 = wsl + (2 * 4 + i_l) * 512 + kh * 256;
  const float bR = bhh[i], bZ = bhh[i + 512], bN = bhh[i + 1024];
  u32 bt = 0;
  for (int t = 0; t < SS; ++t) {
    // stage h: ATOMIC u64 loads from ring slot t (4096 per block)
    const u64* hsrc = (const u64*)(hring + (size_t)t * 16384);
    #pragma unroll
    for (int j = 0; j < 16; ++j) {
      int idx = j * 256 + tid;
      u64 v = ald_u8(hsrc + idx);
      int bb = idx >> 7, m = (idx & 127) * 4;
      *(float4*)&hs[bb * HP + m] = make_float4(
        bf2f((u16)v), bf2f((u16)(v >> 16)), bf2f((u16)(v >> 32)), bf2f((u16)(v >> 48)));
    }
    __syncthreads();
    float aR = 0.f, aZ = 0.f, aN = 0.f;
    const float* hb = hs + b * HP + kh * 256;
    for (int k8 = 0; k8 < 32; ++k8) {
      float4 h0 = *(const float4*)&hb[k8*8], h1 = *(const float4*)&hb[k8*8+4];
      aR = fma44(aR, *(const float4*)&w0[k8*8], *(const float4*)&w0[k8*8+4], h0, h1);
      aZ = fma44(aZ, *(const float4*)&w1[k8*8], *(const float4*)&w1[k8*8+4], h0, h1);
      aN = fma44(aN, *(const float4*)&w2[k8*8], *(const float4*)&w2[k8*8+4], h0, h1);
    }
    aR += __shfl_xor(aR, 1);
    aZ += __shfl_xor(aZ, 1);
    aN += __shfl_xor(aN, 1);
    if (kh == 0) {
      const size_t g = ((size_t)t * 32 + b) * G3;
      float r = sigf (bf2f(gi[g +        i]) + aR + bR);
      float z = sigf (bf2f(gi[g +  512 + i]) + aZ + bZ);
      float n = tanh_(bf2f(gi[g + 1024 + i]) + r * (aN + bN));
      float h2 = z * hs[b * HP + i] + (1.f - z) * n;
      enc_outs[((size_t)b * 256 + t) * 512 + i] = f2bf(h2);  // cross-kernel: plain OK
      h2t[i_l][b] = h2;
    }
    __syncthreads();
    if (tid < 64) {  // write slot t+1: 64 atomic u32 stores per block
      int p = tid >> 5, bq = tid & 31;
      u32 pk = (u32)f2bf(h2t[2*p][bq]) | ((u32)f2bf(h2t[2*p+1][bq]) << 16);
      ast_u((u32*)(hring + (size_t)(t + 1) * 16384) + bq * 256 + bid * 2 + p, pk);
    }
    bt += 128; grid_bar(bar, bt);
  }
}

// ---------- K3: enc_proj = enc_outs @ attn_W2^T + b2 ----------
__global__ __launch_bounds__(256)
void k_proj(const u16* __restrict__ A, const float* __restrict__ W,
            const float* __restrict__ bias, u16* __restrict__ Out)
{
  __shared__ float es[16][HH];
  const int tid = threadIdx.x;
  const int r0 = blockIdx.y * 16;
  #pragma unroll
  for (int j = 0; j < 4; ++j) {
    int u = j * 256 + tid;
    int row = u >> 6, k = (u & 63) * 8;
    float d[8]; unp8(d, *(const uint4*)(A + (size_t)(r0 + row) * HH + k));
    *(float4*)&es[row][k]     = make_float4(d[0],d[1],d[2],d[3]);
    *(float4*)&es[row][k + 4] = make_float4(d[4],d[5],d[6],d[7]);
  }
  __syncthreads();
  const int jl = tid & 63;
  const int rg = (tid >> 6) << 2;
  const int jbase = blockIdx.x * 256 + jl;
  float acc[4][4];
  #pragma unroll
  for (int jj = 0; jj < 4; ++jj) {
    float bv = bias[jbase + jj * 64];
    #pragma unroll
    for (int rr = 0; rr < 4; ++rr) acc[jj][rr] = bv;
  }
  const float4* w0 = (const float4*)(W + (size_t)(jbase      ) * HH);
  const float4* w1 = (const float4*)(W + (size_t)(jbase +  64) * HH);
  const float4* w2 = (const float4*)(W + (size_t)(jbase + 128) * HH);
  const float4* w3 = (const float4*)(W + (size_t)(jbase + 192) * HH);
  for (int k4 = 0; k4 < HH / 4; ++k4) {
    float4 wv0 = w0[k4], wv1 = w1[k4], wv2 = w2[k4], wv3 = w3[k4];
    #pragma unroll
    for (int rr = 0; rr < 4; ++rr) {
      float4 e = *(const float4*)&es[rg + rr][k4 * 4];
      acc[0][rr] = dot4(acc[0][rr], wv0, e);
      acc[1][rr] = dot4(acc[1][rr], wv1, e);
      acc[2][rr] = dot4(acc[2][rr], wv2, e);
      acc[3][rr] = dot4(acc[3][rr], wv3, e);
    }
  }
  #pragma unroll
  for (int rr = 0; rr < 4; ++rr)
    #pragma unroll
    for (int jj = 0; jj < 4; ++jj)
      Out[(size_t)(r0 + rg + rr) * HH + jbase + jj * 64] = f2bf(acc[jj][rr]);
}

// ---------- K4: decoder scan — persistent, 128 blocks, 3 bars/step -------
// Flash-partial ctx (write-once, no atomicAdd) + ATOMIC consumer loads.
__global__ __launch_bounds__(256)
void k_dec_scan(const u16* __restrict__ gi, u16* __restrict__ hring,
                const float* __restrict__ W1, const float* __restrict__ b1,
                const float* __restrict__ av,
                const u16* __restrict__ enc_proj, const u16* __restrict__ enc_outs,
                const float* __restrict__ Whh, const float* __restrict__ Wih,
                const float* __restrict__ bhh,
                float* __restrict__ aring, u16* __restrict__ ctxP,
                float* __restrict__ sringP, u16* __restrict__ h2bf,
                u32* __restrict__ bar)
{
  __shared__ float hs[32 * HP];     // 66.0 KB
  __shared__ u16  csb[32 * CP];     // 33.3 KB (bf16 ctx)
  __shared__ u16  wlds[28 * 512];   // 28.7 KB
  __shared__ float as_[512], vs_[512];
  __shared__ float scq[4][64], wts[64];
  __shared__ float rs[32];
  __shared__ float h2t[4][32];
  const int tid = threadIdx.x;
  const int bid = blockIdx.x;
  const int i_l = tid >> 6, lane = tid & 63, b = lane >> 1, kh = lane & 1;
  const int i0 = bid * 4;
  const int i = i0 + i_l;
  const int pb = bid >> 2, sq = bid & 3;
  vs_[tid] = av[tid]; vs_[tid + 256] = av[tid + 256];
  // stage 28 weight rows once (f32 -> bf16): 3584 float4 = 14/thread
  #pragma unroll
  for (int j = 0; j < 14; ++j) {
    int idx = j * 256 + tid;
    int row = idx >> 7, k4 = idx & 127;
    const float* src;
    if (row < 4)        src = W1  + (size_t)(i0 + row) * 512 + k4 * 4;
    else if (row < 16) { int rr = row - 4;
                         src = Whh + (size_t)((rr >> 2) * 512 + i0 + (rr & 3)) * 512 + k4 * 4; }
    else               { int rr = row - 16;
                         src = Wih + (size_t)((rr >> 2) * 512 + i0 + (rr & 3)) * 768 + 256 + k4 * 4; }
    float4 w = *(const float4*)src;
    int f = row * 512 + k4 * 4;
    wlds[f] = f2bf(w.x); wlds[f+1] = f2bf(w.y); wlds[f+2] = f2bf(w.z); wlds[f+3] = f2bf(w.w);
  }
  const u16* w1r = wlds + (     i_l) * 512 + kh * 256;
  const u16* whr = wlds + ( 4 + i_l) * 512 + kh * 256;
  const u16* whz = wlds + ( 8 + i_l) * 512 + kh * 256;
  const u16* whn = wlds + (12 + i_l) * 512 + kh * 256;
  const u16* wir = wlds + (16 + i_l) * 512 + kh * 256;
  const u16* wiz = wlds + (20 + i_l) * 512 + kh * 256;
  const u16* win = wlds + (24 + i_l) * 512 + kh * 256;
  const float bR = bhh[i], bZ = bhh[i + 512], bN = bhh[i + 1024];
  const float b1i = b1[i];
  u32 bt = 0;
  for (int t = 0; t < TT; ++t) {
    // stage h: ATOMIC u64 loads from ring slot 256+t
    const u64* hsrc = (const u64*)(hring + (size_t)(256 + t) * 16384);
    #pragma unroll
    for (int j = 0; j < 16; ++j) {
      int idx = j * 256 + tid;
      u64 v = ald_u8(hsrc + idx);
      int bb = idx >> 7, m = (idx & 127) * 4;
      *(float4*)&hs[bb * HP + m] = make_float4(
        bf2f((u16)v), bf2f((u16)(v >> 16)), bf2f((u16)(v >> 32)), bf2f((u16)(v >> 48)));
    }
    __syncthreads();
    // ---- P1: a[b,i] = b1[i] + h . W1[i,:] -> a-ring (atomic store) ----
    {
      const float* hb = hs + b * HP + kh * 256;
      float acc = 0.f;
      for (int k8 = 0; k8 < 32; ++k8) {
        float wf[8]; unp8(wf, *(const uint4*)(w1r + k8 * 8));
        acc = fma8(acc, wf, *(const float4*)&hb[k8*8], *(const float4*)&hb[k8*8+4]);
      }
      acc += __shfl_xor(acc, 1);
      if (kh == 0) ast_f(&aring[(size_t)t * 16384 + b * 512 + i], acc + b1i);
    }
    bt += 128; grid_bar(bar, bt);
    // ---- P2: scores -> exp -> PARTIAL ctx/S to unique slots (pb,sq) ----
    {
      u64 v = ald_u8((const u64*)(aring + (size_t)t * 16384 + pb * 512) + tid);
      union { u64 q; float f[2]; } cv; cv.q = v;
      as_[2 * tid] = cv.f[0]; as_[2 * tid + 1] = cv.f[1];
    }
    __syncthreads();
    {
      const int kp = tid >> 6, s_l = tid & 63;
      const int s = sq * 64 + s_l;
      const u16* pr = enc_proj + ((size_t)pb * 256 + s) * 512 + kp * 128;
      const float* ak = as_ + kp * 128;
      const float* vk = vs_ + kp * 128;
      float acc = 0.f;
      for (int k8 = 0; k8 < 16; ++k8) {
        float d[8]; unp8(d, *(const uint4*)(pr + k8 * 8));
        #pragma unroll
        for (int e = 0; e < 8; ++e)
          acc += vk[k8 * 8 + e] * tanh_(d[e] + ak[k8 * 8 + e]);
      }
      scq[kp][s_l] = acc;
    }
    __syncthreads();
    if (tid < 64) {
      float sc = (scq[0][tid] + scq[1][tid]) + (scq[2][tid] + scq[3][tid]);
      float e = __expf(sc);          // bounded scores: no max-shift (proven r7)
      wts[tid] = e;
      float su = e;
      #pragma unroll
      for (int d = 1; d < 64; d <<= 1) su += __shfl_xor(su, d);
      if (tid == 0) ast_f(&sringP[t * 128 + sq * 32 + pb], su);
    }
    __syncthreads();
    {
      const int k0 = tid * 2;
      float c0 = 0.f, c1 = 0.f;
      const u16* eo = enc_outs + ((size_t)pb * 256 + sq * 64) * 512 + k0;
      for (int s = 0; s < 64; ++s) {
        float w = wts[s];
        u32 pair = *(const u32*)(eo + (size_t)s * 512);
        c0 = fmaf(w, blo(pair), c0);
        c1 = fmaf(w, bhi(pair), c1);
      }
      // partial ctx (unnormalized, bf16) -> unique slot [t][sq*32+pb]
      u32 pk = (u32)f2bf(c0) | ((u32)f2bf(c1) << 16);
      ast_u((u32*)(ctxP + (size_t)t * 65536 + (sq * 32 + pb) * 512 + k0), pk);
    }
    bt += 128; grid_bar(bar, bt);
    // ---- P3: combine 4 partials (ATOMIC loads) -> bf16 LDS, GRU cell ----
    if (tid < 32) {
      const float* sp = sringP + t * 128;
      rs[tid] = 1.f / ((ald_f(sp + tid) + ald_f(sp + 32 + tid)) +
                       (ald_f(sp + 64 + tid) + ald_f(sp + 96 + tid)));
    }
    __syncthreads();
    #pragma unroll
    for (int j = 0; j < 8; ++j) {       // 2048 chunks: 32 b x 64 (8 bf16 each)
      int idx = j * 256 + tid;
      int bb = idx >> 6, m = (idx & 63) * 8;
      const u64* bp = (const u64*)(ctxP + (size_t)t * 65536 + bb * 512 + m);
      float c[8] = {0,0,0,0,0,0,0,0};
      #pragma unroll
      for (int q = 0; q < 4; ++q) {     // partial q at +q*4096 u64
        u64 v0 = ald_u8(bp + q * 4096);
        u64 v1 = ald_u8(bp + q * 4096 + 1);
        c[0] += bf2f((u16)v0); c[1] += bf2f((u16)(v0 >> 16));
        c[2] += bf2f((u16)(v0 >> 32)); c[3] += bf2f((u16)(v0 >> 48));
        c[4] += bf2f((u16)v1); c[5] += bf2f((u16)(v1 >> 16));
        c[6] += bf2f((u16)(v1 >> 32)); c[7] += bf2f((u16)(v1 >> 48));
      }
      float r = rs[bb];
      *(u32*)&csb[bb * CP + m]     = (u32)f2bf(c[0]*r) | ((u32)f2bf(c[1]*r) << 16);
      *(u32*)&csb[bb * CP + m + 2] = (u32)f2bf(c[2]*r) | ((u32)f2bf(c[3]*r) << 16);
      *(u32*)&csb[bb * CP + m + 4] = (u32)f2bf(c[4]*r) | ((u32)f2bf(c[5]*r) << 16);
      *(u32*)&csb[bb * CP + m + 6] = (u32)f2bf(c[6]*r) | ((u32)f2bf(c[7]*r) << 16);
    }
    __syncthreads();
    {
      const float* hb = hs + b * HP + kh * 256;
      const u16*   cb = csb + b * CP + kh * 256;
      float hR=0.f,hZ=0.f,hN=0.f,cR=0.f,cZ=0.f,cN=0.f;
      for (int k8 = 0; k8 < 32; ++k8) {
        float4 h0 = *(const float4*)&hb[k8*8], h1 = *(const float4*)&hb[k8*8+4];
        float cf[8]; unp8(cf, *(const uint4*)(cb + k8 * 8));
        float wf[8];
        unp8(wf, *(const uint4*)(whr + k8 * 8)); hR = fma8(hR, wf, h0, h1);
        unp8(wf, *(const uint4*)(whz + k8 * 8)); hZ = fma8(hZ, wf, h0, h1);
        unp8(wf, *(const uint4*)(whn + k8 * 8)); hN = fma8(hN, wf, h0, h1);
        unp8(wf, *(const uint4*)(wir + k8 * 8)); cR = fma8p(cR, wf, cf);
        unp8(wf, *(const uint4*)(wiz + k8 * 8)); cZ = fma8p(cZ, wf, cf);
        unp8(wf, *(const uint4*)(win + k8 * 8)); cN = fma8p(cN, wf, cf);
      }
      hR += __shfl_xor(hR, 1); hZ += __shfl_xor(hZ, 1); hN += __shfl_xor(hN, 1);
      cR += __shfl_xor(cR, 1); cZ += __shfl_xor(cZ, 1); cN += __shfl_xor(cN, 1);
      if (kh == 0) {
        const size_t g = ((size_t)t * 32 + b) * G3;
        float r = sigf (bf2f(gi[g +        i]) + cR + hR + bR);
        float z = sigf (bf2f(gi[g +  512 + i]) + cZ + hZ + bZ);
        float n = tanh_(bf2f(gi[g + 1024 + i]) + cN + r * (hN + bN));
        float h2 = z * hs[b * HP + i] + (1.f - z) * n;
        h2bf[((size_t)t * 32 + b) * 512 + i] = f2bf(h2);   // cross-kernel: plain OK
        h2t[i_l][b] = h2;
      }
    }
    __syncthreads();
    if (tid < 64) {   // carry -> ring slot 257+t
      int p = tid >> 5, bq = tid & 31;
      u32 pk = (u32)f2bf(h2t[2*p][bq]) | ((u32)f2bf(h2t[2*p+1][bq]) << 16);
      ast_u((u32*)(hring + (size_t)(257 + t) * 16384) + bq * 256 + bid * 2 + p, pk);
    }
    bt += 128; grid_bar(bar, bt);
  }
}

// ---------- K5: fcW f32 -> bf16 (one-time) ----------
__global__ __launch_bounds__(256)
void k_cvt(const float* __restrict__ in, u16* __restrict__ out)
{
  size_t i = ((size_t)blockIdx.x * 256 + threadIdx.x) * 8;
  float4 a = *(const float4*)(in + i);
  float4 b = *(const float4*)(in + i + 4);
  union { uint4 v; u16 s[8]; } u;
  u.s[0]=f2bf(a.x); u.s[1]=f2bf(a.y); u.s[2]=f2bf(a.z); u.s[3]=f2bf(a.w);
  u.s[4]=f2bf(b.x); u.s[5]=f2bf(b.y); u.s[6]=f2bf(b.z); u.s[7]=f2bf(b.w);
  *(uint4*)(out + i) = u.v;
}

// ---------- K6: logits via bf16 MFMA (proven r8/r9) ----------
__global__ __launch_bounds__(256)
void k_logits_mfma(const u16* __restrict__ A, const u16* __restrict__ Wb,
                   const float* __restrict__ bias, float* __restrict__ out)
{
  __shared__ u16 Al[64 * 512];    // 64 KB
  const int tid = threadIdx.x;
  const int r0 = blockIdx.x * 64;
  const int v0 = blockIdx.y * 64;
  {
    const uint4* src = (const uint4*)(A + (size_t)r0 * 512);
    uint4* dst = (uint4*)Al;
    #pragma unroll
    for (int j = 0; j < 16; ++j) {
      int idx = j * 256 + tid;
      int row = idx >> 6, g = idx & 63;
      dst[(row << 6) | (g ^ (row & 7))] = src[idx];
    }
  }
  const int w  = tid >> 6, l = tid & 63;
  const int lr = l & 15,  qk = l >> 4;
  const int v  = v0 + w * 16 + lr;
  frag bfr[16];
  {
    const u16* wrow = Wb + (size_t)v * 512 + qk * 8;
    #pragma unroll
    for (int ks = 0; ks < 16; ++ks)
      bfr[ks] = *(const frag*)(wrow + ks * 32);
  }
  const float bv = bias[v];
  __syncthreads();
  f32x4v acc[4];
  #pragma unroll
  for (int mt = 0; mt < 4; ++mt) acc[mt] = (f32x4v){0.f, 0.f, 0.f, 0.f};
  #pragma unroll
  for (int ks = 0; ks < 16; ++ks) {
    #pragma unroll
    for (int mt = 0; mt < 4; ++mt) {
      const int row = mt * 16 + lr;
      const int gr  = ks * 4 + qk;
      frag a = *(const frag*)&Al[(row << 9) | ((gr ^ (row & 7)) << 3)];
      acc[mt] = __builtin_amdgcn_mfma_f32_16x16x32_bf16(a, bfr[ks], acc[mt], 0, 0, 0);
    }
  }
  #pragma unroll
  for (int mt = 0; mt < 4; ++mt)
    #pragma unroll
    for (int reg = 0; reg < 4; ++reg) {
      const int r = r0 + mt * 16 + qk * 4 + reg;         // r = t*32 + b
      out[(size_t)(r & 31) * 64 * VV + (size_t)(r >> 5) * VV + v] = acc[mt][reg] + bv;
    }
}

// ---------- launch ----------
extern "C" void kernel_launch(void* const* d_in, const int* in_sizes, int n_in,
                              void* d_out, int out_size, void* d_ws, size_t ws_size,
                              hipStream_t stream) {
  (void)in_sizes; (void)n_in; (void)out_size; (void)ws_size;
  const int*   src  = (const int*)d_in[0];
  const int*   tgt  = (const int*)d_in[1];
  const float* eemb = (const float*)d_in[2];
  const float* eWih = (const float*)d_in[3];
  const float* eWhh = (const float*)d_in[4];
  const float* ebih = (const float*)d_in[5];
  const float* ebhh = (const float*)d_in[6];
  const float* demb = (const float*)d_in[7];
  const float* aW1  = (const float*)d_in[8];
  const float* ab1  = (const float*)d_in[9];
  const float* aW2  = (const float*)d_in[10];
  const float* ab2  = (const float*)d_in[11];
  const float* av   = (const float*)d_in[12];
  const float* dWih = (const float*)d_in[13];
  const float* dWhh = (const float*)d_in[14];
  const float* dbih = (const float*)d_in[15];
  const float* dbhh = (const float*)d_in[16];
  const float* fcW  = (const float*)d_in[17];
  const float* fcb  = (const float*)d_in[18];
  float* out = (float*)d_out;

  // workspace carve (~71 MiB). All rings write-once per launch.
  float* aring   = (float*)d_ws;                 // 64 x 16384 f32 (4 MiB)
  float* sringP  = aring + 1048576;              // 64 x 128 f32 (32 KiB)
  u32*   bars    = (u32*)(sringP + 8192);        // 8 u32
  u16*  ctxP     = (u16*)(bars + 8);             // 64 x 128 x 512 u16 (8 MiB)
  u16*  hring    = ctxP + 4194304;               // 321 x 16384 u16 (10.5 MiB)
  u16*  h2bf     = hring + 5259264;              // 1,048,576 u16
  u16*  gi_enc   = h2bf + 1048576;               // 12,582,912 u16
  u16*  gi_dec   = gi_enc + 12582912;            //  3,145,728 u16
  u16*  enc_outs = gi_dec + 3145728;             //  4,194,304 u16
  u16*  enc_proj = enc_outs + 4194304;           //  4,194,304 u16
  u16*  wbf      = gi_enc;  // aliases gi_*/... (dead after k_dec_scan)

  // h0 slot memset is safe: consumers read it via ATOMIC loads (L2-bypass).
  hipMemsetAsync(hring, 0, 16384 * sizeof(u16), stream);   // h0 slot (zeros)
  hipMemsetAsync(bars, 0, 8 * sizeof(u32), stream);        // barrier counters

  k_embed_gemm<<<dim3(6, 512), 256, 0, stream>>>(src, SS, eemb, eWih, EE,  ebih, gi_enc);
  k_embed_gemm<<<dim3(6, 128), 256, 0, stream>>>(tgt, TT, demb, dWih, 768, dbih, gi_dec);

  k_enc_scan<<<128, 256, 0, stream>>>(gi_enc, eWhh, ebhh, hring, enc_outs, bars + 0);

  k_proj<<<dim3(2, 512), 256, 0, stream>>>(enc_outs, aW2, ab2, enc_proj);

  k_dec_scan<<<128, 256, 0, stream>>>(gi_dec, hring, aW1, ab1, av,
                                      enc_proj, enc_outs, dWhh, dWih, dbhh,
                                      aring, ctxP, sringP, h2bf, bars + 1);

  k_cvt<<<8000, 256, 0, stream>>>(fcW, wbf);

  k_logits_mfma<<<dim3(32, 500), 256, 0, stream>>>(h2bf, wbf, fcb, out);
}